// Round 1
// baseline (232.014 us; speedup 1.0000x reference)
//
#include <hip/hip_runtime.h>

// WKV (RWKV v4) as a 3-pass chunked parallel scan over T=1024.
// NCH=64 chunks of CHL=16 steps, 4 channels/thread (float4, 16B/lane).
//
// Kernel A (wkv_states): per-chunk local states from identity.
//   262144 threads = 1024 wg -> 4 wg/CU (2x the previous occupancy).
// Kernel B (wkv_scan): in-place exclusive prefix scan over the 64 chunk
//   states per (b,c). 4096 threads; removes the O(j) serial combine that
//   previously ran inside every emit thread (load-imbalanced, exp-chained).
// Kernel C (wkv_emit): load initial state (48B), rescan chunk, emit y.
//
// All state kept in log2 domain: w,u,k pre-scaled by log2(e) so every
// exponential is a single v_exp_f32 (exp2f) with no preceding multiply.
//
// Chunk composition (stabilized, per-channel decay w, L=CHL):
//   pn  = max(pp0 + L*w, cm)
//   aa' = 2^{pp0+Lw-pn} aa0 + 2^{cm-pn} ca     (bb likewise)

#define T_FIX  1024
#define NCH    64
#define CHL    (T_FIX / NCH)   // 16
#define BATCH  8
#define SBATCH 8
#define L2E    1.4426950408889634f

__device__ __forceinline__ void wkv_step2(float& aa, float& bb, float& pp,
                                          float w2, float k2, float vt)
{
    float ww2 = pp + w2;
    float q2  = fmaxf(ww2, k2);
    float e1  = exp2f(ww2 - q2);
    float e2  = exp2f(k2 - q2);
    aa = fmaf(e1, aa, e2 * vt);
    bb = fmaf(e1, bb, e2);
    pp = q2;
}

#define F4TOA(a, f) { a[0] = (f).x; a[1] = (f).y; a[2] = (f).z; a[3] = (f).w; }

__global__ __launch_bounds__(256)
void wkv_states(const float* __restrict__ td,
                const float* __restrict__ k,
                const float* __restrict__ v,
                float* __restrict__ aa_s,
                float* __restrict__ bb_s,
                float* __restrict__ pp_s,
                int B, int C)
{
    const int C4  = C >> 2;
    int gid = blockIdx.x * blockDim.x + threadIdx.x;
    if (gid >= B * NCH * C4) return;
    int c4  = gid % C4;
    int rem = gid / C4;
    int j   = rem % NCH;
    int b   = rem / NCH;
    int c   = c4 << 2;

    float4 tdv = *(const float4*)(td + c);
    float w2[4] = { -__expf(tdv.x) * L2E, -__expf(tdv.y) * L2E,
                    -__expf(tdv.z) * L2E, -__expf(tdv.w) * L2E };

    const size_t base = ((size_t)b * T_FIX + (size_t)j * CHL) * C + c;
    const float* kp = k + base;
    const float* vp = v + base;

    float aa[4] = {0.f, 0.f, 0.f, 0.f};
    float bb[4] = {0.f, 0.f, 0.f, 0.f};
    float pp[4] = {-1e38f, -1e38f, -1e38f, -1e38f};

    for (int tb = 0; tb < CHL; tb += BATCH) {
        float4 kb[BATCH], vb[BATCH];
        #pragma unroll
        for (int i = 0; i < BATCH; ++i) {
            kb[i] = *(const float4*)(kp + (size_t)(tb + i) * C);
            vb[i] = *(const float4*)(vp + (size_t)(tb + i) * C);
        }
        #pragma unroll
        for (int i = 0; i < BATCH; ++i) {
            float ka[4], va[4];
            F4TOA(ka, kb[i]); F4TOA(va, vb[i]);
            #pragma unroll
            for (int cc = 0; cc < 4; ++cc)
                wkv_step2(aa[cc], bb[cc], pp[cc], w2[cc], ka[cc] * L2E, va[cc]);
        }
    }

    size_t sidx = ((size_t)j * B + b) * C + c;
    *(float4*)(aa_s + sidx) = make_float4(aa[0], aa[1], aa[2], aa[3]);
    *(float4*)(bb_s + sidx) = make_float4(bb[0], bb[1], bb[2], bb[3]);
    *(float4*)(pp_s + sidx) = make_float4(pp[0], pp[1], pp[2], pp[3]);
}

// In-place exclusive prefix scan over chunk states along j, per (b, c).
// Slot j is overwritten with combine(chunk_0 .. chunk_{j-1}) (identity at j=0).
__global__ __launch_bounds__(256)
void wkv_scan(const float* __restrict__ td,
              float* __restrict__ aa_s,
              float* __restrict__ bb_s,
              float* __restrict__ pp_s,
              int B, int C)
{
    const int C4 = C >> 2;
    int gid = blockIdx.x * blockDim.x + threadIdx.x;
    if (gid >= B * C4) return;
    int c4 = gid % C4;
    int b  = gid / C4;
    int c  = c4 << 2;

    float4 tdv = *(const float4*)(td + c);
    // L*w in log2 units
    float wL[4] = { -__expf(tdv.x) * (L2E * (float)CHL),
                    -__expf(tdv.y) * (L2E * (float)CHL),
                    -__expf(tdv.z) * (L2E * (float)CHL),
                    -__expf(tdv.w) * (L2E * (float)CHL) };

    float aa[4] = {0.f, 0.f, 0.f, 0.f};
    float bb[4] = {0.f, 0.f, 0.f, 0.f};
    float pp[4] = {-1e38f, -1e38f, -1e38f, -1e38f};

    for (int jb = 0; jb < NCH; jb += SBATCH) {
        float4 ca4[SBATCH], cb4[SBATCH], cm4[SBATCH];
        #pragma unroll
        for (int i = 0; i < SBATCH; ++i) {
            size_t sidx = ((size_t)(jb + i) * B + b) * C + c;
            ca4[i] = *(const float4*)(aa_s + sidx);
            cb4[i] = *(const float4*)(bb_s + sidx);
            cm4[i] = *(const float4*)(pp_s + sidx);
        }
        #pragma unroll
        for (int i = 0; i < SBATCH; ++i) {
            size_t sidx = ((size_t)(jb + i) * B + b) * C + c;
            // write exclusive prefix (state BEFORE absorbing chunk jb+i)
            *(float4*)(aa_s + sidx) = make_float4(aa[0], aa[1], aa[2], aa[3]);
            *(float4*)(bb_s + sidx) = make_float4(bb[0], bb[1], bb[2], bb[3]);
            *(float4*)(pp_s + sidx) = make_float4(pp[0], pp[1], pp[2], pp[3]);
            float ca[4], cb[4], cm[4];
            F4TOA(ca, ca4[i]); F4TOA(cb, cb4[i]); F4TOA(cm, cm4[i]);
            #pragma unroll
            for (int cc = 0; cc < 4; ++cc) {
                float ppd = pp[cc] + wL[cc];
                float pn  = fmaxf(ppd, cm[cc]);
                float ea  = exp2f(ppd - pn);
                float eb  = exp2f(cm[cc] - pn);
                aa[cc] = fmaf(ea, aa[cc], eb * ca[cc]);
                bb[cc] = fmaf(ea, bb[cc], eb * cb[cc]);
                pp[cc] = pn;
            }
        }
    }
}

__global__ __launch_bounds__(256)
void wkv_emit(const float* __restrict__ td,
              const float* __restrict__ tf,
              const float* __restrict__ k,
              const float* __restrict__ v,
              const float* __restrict__ aa_s,
              const float* __restrict__ bb_s,
              const float* __restrict__ pp_s,
              float* __restrict__ y,
              int B, int C)
{
    const int C4  = C >> 2;
    int gid = blockIdx.x * blockDim.x + threadIdx.x;
    if (gid >= B * NCH * C4) return;
    int c4  = gid % C4;
    int rem = gid / C4;
    int j   = rem % NCH;
    int b   = rem / NCH;
    int c   = c4 << 2;

    float4 tdv = *(const float4*)(td + c);
    float4 tfv = *(const float4*)(tf + c);
    float w2[4] = { -__expf(tdv.x) * L2E, -__expf(tdv.y) * L2E,
                    -__expf(tdv.z) * L2E, -__expf(tdv.w) * L2E };
    float u2[4] = { tfv.x * L2E, tfv.y * L2E, tfv.z * L2E, tfv.w * L2E };

    // initial state = precomputed exclusive prefix (one 48B load)
    size_t sidx = ((size_t)j * B + b) * C + c;
    float4 a4 = *(const float4*)(aa_s + sidx);
    float4 b4 = *(const float4*)(bb_s + sidx);
    float4 p4 = *(const float4*)(pp_s + sidx);
    float aa[4], bb[4], pp[4];
    F4TOA(aa, a4); F4TOA(bb, b4); F4TOA(pp, p4);

    const size_t base = ((size_t)b * T_FIX + (size_t)j * CHL) * C + c;
    const float* kp = k + base;
    const float* vp = v + base;
    float*       yp = y + base;

    for (int tb = 0; tb < CHL; tb += BATCH) {
        float4 kb[BATCH], vb[BATCH];
        #pragma unroll
        for (int i = 0; i < BATCH; ++i) {
            kb[i] = *(const float4*)(kp + (size_t)(tb + i) * C);
            vb[i] = *(const float4*)(vp + (size_t)(tb + i) * C);
        }
        #pragma unroll
        for (int i = 0; i < BATCH; ++i) {
            float ka[4], va[4], ya[4];
            F4TOA(ka, kb[i]); F4TOA(va, vb[i]);
            #pragma unroll
            for (int cc = 0; cc < 4; ++cc) {
                float k2 = ka[cc] * L2E;
                float ww = u2[cc] + k2;
                float q  = fmaxf(pp[cc], ww);
                float e1 = exp2f(pp[cc] - q);
                float e2 = exp2f(ww - q);
                ya[cc] = __fdividef(fmaf(e1, aa[cc], e2 * va[cc]),
                                    fmaf(e1, bb[cc], e2));
                wkv_step2(aa[cc], bb[cc], pp[cc], w2[cc], k2, va[cc]);
            }
            *(float4*)(yp + (size_t)(tb + i) * C) = make_float4(ya[0], ya[1], ya[2], ya[3]);
        }
    }
}

extern "C" void kernel_launch(void* const* d_in, const int* in_sizes, int n_in,
                              void* d_out, int out_size, void* d_ws, size_t ws_size,
                              hipStream_t stream)
{
    const float* td = (const float*)d_in[3];
    const float* tf = (const float*)d_in[4];
    const float* k  = (const float*)d_in[5];
    const float* v  = (const float*)d_in[6];
    float*       y  = (float*)d_out;

    const int C   = in_sizes[3];
    const int BTC = in_sizes[5];
    const int B   = BTC / (T_FIX * C);

    const size_t N = (size_t)B * C * NCH;
    float* aa_s = (float*)d_ws;
    float* bb_s = aa_s + N;
    float* pp_s = bb_s + N;

    const int block = 256;

    const int threadsA = B * NCH * (C >> 2);
    const int gridA    = (threadsA + block - 1) / block;

    const int threadsS = B * (C >> 2);
    const int gridS    = (threadsS + block - 1) / block;

    wkv_states<<<gridA, block, 0, stream>>>(td, k, v, aa_s, bb_s, pp_s, B, C);
    wkv_scan  <<<gridS, block, 0, stream>>>(td, aa_s, bb_s, pp_s, B, C);
    wkv_emit  <<<gridA, block, 0, stream>>>(td, tf, k, v, aa_s, bb_s, pp_s, y, B, C);
}